// Round 4
// baseline (148.574 us; speedup 1.0000x reference)
//
#include <hip/hip_runtime.h>
#include <hip/hip_bf16.h>
#include <hip/hip_cooperative_groups.h>

namespace cg = cooperative_groups;

typedef __attribute__((ext_vector_type(8))) short short8v;
typedef __attribute__((ext_vector_type(4))) float f32x4;

#define L_SEQ 2048
#define D_DIM 1024
#define N_DIM 16
#define T_CHUNK 32
#define NCHUNK (L_SEQ / T_CHUNK)  // 64
#define EPS_DISC 1e-9f

__device__ __forceinline__ float softplusf(float x) {
    return (x > 15.f) ? x : __logf(1.f + __expf(x));
}

__device__ __forceinline__ unsigned short f2bf(float f) {
    unsigned int u = __float_as_uint(f);
    u += 0x7FFFu + ((u >> 16) & 1u);   // RNE
    return (unsigned short)(u >> 16);
}
__device__ __forceinline__ unsigned int pack2(float a, float b) {
    return (unsigned int)f2bf(a) | ((unsigned int)f2bf(b) << 16);
}

// ===================== Phase A: one params tile ==============================
// tile<128: dt GEMM tile (BM=BN=128,BK=32 bf16 MFMA); tile<384: B/C GEMV;
// else: h0 matvec rows.
__device__ void phaseA_tile(int tile, unsigned int* As, unsigned int* Bs,
                            const float* __restrict__ u,
                            const float* __restrict__ dt_w, const float* __restrict__ dt_b,
                            const float* __restrict__ B_w, const float* __restrict__ B_b,
                            const float* __restrict__ C_w, const float* __restrict__ C_b,
                            const float* __restrict__ init_w, const float* __restrict__ init_b,
                            float* __restrict__ dt, float* __restrict__ Bm,
                            float* __restrict__ Cm, float* __restrict__ h0) {
    const int t = threadIdx.x;
    if (tile < 128) {
        const int bm   = tile & 15;
        const int bn   = tile >> 4;
        const int row  = t >> 1;
        const int half = t & 1;
        const int swz  = (row >> 1) & 3;
        const int lane = t & 63;
        const int wid  = t >> 6;
        const int wm   = wid >> 1, wn = wid & 1;
        const int lrow = lane & 15, lq = lane >> 4;

        const float* uptr = u + (bm * 128 + row) * 1024 + half * 16;
        const float* wptr = dt_w + (bn * 128 + row) * 1024 + half * 16;

        f32x4 acc[4][4];
#pragma unroll
        for (int mi = 0; mi < 4; ++mi)
#pragma unroll
            for (int ni = 0; ni < 4; ++ni) acc[mi][ni] = (f32x4){0.f, 0.f, 0.f, 0.f};

        for (int k0 = 0; k0 < 1024; k0 += 32) {
            __syncthreads();
            {
                const float4* p = (const float4*)(uptr + k0);
                float4 a0 = p[0], a1 = p[1], a2 = p[2], a3 = p[3];
                uint4 c0 = make_uint4(pack2(a0.x, a0.y), pack2(a0.z, a0.w),
                                      pack2(a1.x, a1.y), pack2(a1.z, a1.w));
                uint4 c1 = make_uint4(pack2(a2.x, a2.y), pack2(a2.z, a2.w),
                                      pack2(a3.x, a3.y), pack2(a3.z, a3.w));
                const int kb0 = (half * 2) ^ swz, kb1 = (half * 2 + 1) ^ swz;
                *(uint4*)&As[row * 16 + kb0 * 4] = c0;
                *(uint4*)&As[row * 16 + kb1 * 4] = c1;

                const float4* q = (const float4*)(wptr + k0);
                float4 b0 = q[0], b1 = q[1], b2 = q[2], b3 = q[3];
                uint4 d0 = make_uint4(pack2(b0.x, b0.y), pack2(b0.z, b0.w),
                                      pack2(b1.x, b1.y), pack2(b1.z, b1.w));
                uint4 d1 = make_uint4(pack2(b2.x, b2.y), pack2(b2.z, b2.w),
                                      pack2(b3.x, b3.y), pack2(b3.z, b3.w));
                *(uint4*)&Bs[row * 16 + kb0 * 4] = d0;
                *(uint4*)&Bs[row * 16 + kb1 * 4] = d1;
            }
            __syncthreads();
            short8v af[4], bf[4];
#pragma unroll
            for (int mi = 0; mi < 4; ++mi) {
                const int ar = wm * 64 + mi * 16 + lrow;
                const int kb = lq ^ ((ar >> 1) & 3);
                af[mi] = *(const short8v*)&As[ar * 16 + kb * 4];
            }
#pragma unroll
            for (int ni = 0; ni < 4; ++ni) {
                const int br = wn * 64 + ni * 16 + lrow;
                const int kb = lq ^ ((br >> 1) & 3);
                bf[ni] = *(const short8v*)&Bs[br * 16 + kb * 4];
            }
#pragma unroll
            for (int mi = 0; mi < 4; ++mi)
#pragma unroll
                for (int ni = 0; ni < 4; ++ni)
                    acc[mi][ni] = __builtin_amdgcn_mfma_f32_16x16x32_bf16(af[mi], bf[ni], acc[mi][ni], 0, 0, 0);
        }

#pragma unroll
        for (int mi = 0; mi < 4; ++mi)
#pragma unroll
            for (int ni = 0; ni < 4; ++ni) {
                const int cg_ = bn * 128 + wn * 64 + ni * 16 + lrow;
                const float bv = dt_b[cg_];
#pragma unroll
                for (int j = 0; j < 4; ++j) {
                    const int rg = bm * 128 + wm * 64 + mi * 16 + lq * 4 + j;
                    dt[rg * 1024 + cg_] = softplusf(acc[mi][ni][j] + bv);
                }
            }
        __syncthreads();  // protect As/Bs for a possible next tile
    } else if (tile < 384) {
        const int tid = (tile - 128) * 256 + t;
        const int l = tid >> 5;
        const int col = tid & 31;
        const float* wrow = (col < 16) ? (B_w + col * 1024) : (C_w + (col - 16) * 1024);
        const float4* w4 = (const float4*)wrow;
        const float4* u4 = (const float4*)(u + l * 1024);
        float acc = 0.f;
#pragma unroll 8
        for (int j = 0; j < 256; ++j) {
            float4 a = u4[j], bb = w4[j];
            acc += a.x * bb.x + a.y * bb.y + a.z * bb.z + a.w * bb.w;
        }
        if (col < 16) Bm[l * 16 + col] = acc + B_b[col];
        else          Cm[l * 16 + (col - 16)] = acc + C_b[col - 16];
    } else {
        const int lane = t & 63;
        const int row  = (tile - 384) * 4 + (t >> 6);
        const float4* w4 = (const float4*)(init_w + row * 3072);
        const float4* u4 = (const float4*)u;
        float acc = 0.f;
#pragma unroll
        for (int s = 0; s < 12; ++s) {
            float4 a = w4[s * 64 + lane];
            float4 bb = u4[s * 64 + lane];
            acc += a.x * bb.x + a.y * bb.y + a.z * bb.z + a.w * bb.w;
        }
#pragma unroll
        for (int off = 32; off > 0; off >>= 1) acc += __shfl_down(acc, off);
        if (lane == 0) h0[row] = acc + init_b[row];
    }
}

// ===================== Phase B: scan phase 1 tile (512 tiles) ================
__device__ void phaseB_tile(int tile,
                            const float* __restrict__ dt, const float* __restrict__ Bm,
                            const float* __restrict__ u, const float* __restrict__ A_log,
                            float* __restrict__ ap, float* __restrict__ hl) {
    const int t    = threadIdx.x;
    const int c    = tile >> 3;            // 0..63
    const int dblk = tile & 7;             // 0..7
    const int dd   = t >> 1;
    const int nh   = t & 1;
    const int d    = dblk * 128 + dd;
    float An[8];
#pragma unroll
    for (int n = 0; n < 8; ++n) An[n] = -__expf(A_log[nh * 8 + n]);
    float h[8], p[8];
#pragma unroll
    for (int n = 0; n < 8; ++n) { h[n] = 0.f; p[n] = 1.f; }

    const int l0 = c * T_CHUNK;
    for (int i = 0; i < T_CHUNK; ++i) {
        const int l = l0 + i;
        const float dtld = dt[l * D_DIM + d];
        const float uld  = u[l * D_DIM + d];
        const float4 b0 = *(const float4*)&Bm[l * 16 + nh * 8];
        const float4 b1 = *(const float4*)&Bm[l * 16 + nh * 8 + 4];
        auto body = [&](int n, float bn) {
            const float x = dtld * An[n];
            const float e = __expf(x);
            const float coef = (e - 1.f) * __builtin_amdgcn_rcpf(x + EPS_DISC);
            const float bu = coef * bn * uld;
            p[n] *= e;
            h[n] = fmaf(e, h[n], bu);
        };
        body(0, b0.x); body(1, b0.y); body(2, b0.z); body(3, b0.w);
        body(4, b1.x); body(5, b1.y); body(6, b1.z); body(7, b1.w);
    }
    const int base = c * (D_DIM * N_DIM) + d * 16 + nh * 8;
    *(float4*)&ap[base + 0] = make_float4(p[0], p[1], p[2], p[3]);
    *(float4*)&ap[base + 4] = make_float4(p[4], p[5], p[6], p[7]);
    *(float4*)&hl[base + 0] = make_float4(h[0], h[1], h[2], h[3]);
    *(float4*)&hl[base + 4] = make_float4(h[4], h[5], h[6], h[7]);
}

// ===================== Phase C: chunk-level scan group (256 groups) ==========
__device__ void phaseC_group(int g,
                             const float* __restrict__ h0,
                             float* __restrict__ ap, const float* __restrict__ hl) {
    const int t = threadIdx.x;
    if (t < 64) {
        const int ch = g * 64 + t;
        float h = h0[ch];
#pragma unroll 8
        for (int c = 0; c < NCHUNK; ++c) {
            const int idx = c * (D_DIM * N_DIM) + ch;
            const float a = ap[idx];
            const float b = hl[idx];
            ap[idx] = h;            // carry-in for phase D
            h = fmaf(a, h, b);
        }
    }
}

// ===================== Phase D: recompute + fused epilogue (512 tiles) =======
__device__ void phaseD_tile(int tile,
                            const float* __restrict__ dt, const float* __restrict__ Bm,
                            const float* __restrict__ Cm, const float* __restrict__ u,
                            const float* __restrict__ A_log, const float* __restrict__ hstart,
                            const float* __restrict__ D_w, const float* __restrict__ scale,
                            float* __restrict__ out) {
    const int t    = threadIdx.x;
    const int c    = tile >> 3;
    const int dblk = tile & 7;
    const int dd   = t >> 1;
    const int nh   = t & 1;
    const int d    = dblk * 128 + dd;
    float An[8];
#pragma unroll
    for (int n = 0; n < 8; ++n) An[n] = -__expf(A_log[nh * 8 + n]);
    float h[8];
    const int base = c * (D_DIM * N_DIM) + d * 16 + nh * 8;
    {
        float4 h0v = *(const float4*)&hstart[base + 0];
        float4 h1v = *(const float4*)&hstart[base + 4];
        h[0] = h0v.x; h[1] = h0v.y; h[2] = h0v.z; h[3] = h0v.w;
        h[4] = h1v.x; h[5] = h1v.y; h[6] = h1v.z; h[7] = h1v.w;
    }
    const float scl = fmaxf(scale[0], 0.5f);
    const float dw = D_w[d];
    const int l0 = c * T_CHUNK;
    for (int i = 0; i < T_CHUNK; ++i) {
        const int l = l0 + i;
        const float dtld = dt[l * D_DIM + d];
        const float uld  = u[l * D_DIM + d];
        const float4 b0 = *(const float4*)&Bm[l * 16 + nh * 8];
        const float4 b1 = *(const float4*)&Bm[l * 16 + nh * 8 + 4];
        const float4 c0 = *(const float4*)&Cm[l * 16 + nh * 8];
        const float4 c1 = *(const float4*)&Cm[l * 16 + nh * 8 + 4];
        float y = 0.f;
        auto body = [&](int n, float bn, float cn) {
            const float x = dtld * An[n];
            const float e = __expf(x);
            const float coef = (e - 1.f) * __builtin_amdgcn_rcpf(x + EPS_DISC);
            const float bu = coef * bn * uld;
            h[n] = fmaf(e, h[n], bu);
            y = fmaf(cn, h[n], y);
        };
        body(0, b0.x, c0.x); body(1, b0.y, c0.y); body(2, b0.z, c0.z); body(3, b0.w, c0.w);
        body(4, b1.x, c1.x); body(5, b1.y, c1.y); body(6, b1.z, c1.z); body(7, b1.w, c1.w);
        y += __shfl_xor(y, 1);                 // combine the two n-halves
        if (nh == 0) {
            const float yv = fmaf(dw, uld, y);
            out[l * D_DIM + d] = softplusf(yv) * scl;
        }
    }
}

// ===================== Cooperative mega-kernel (grid-size agnostic) ==========
__global__ __launch_bounds__(256, 2) void fm_mega(const float* __restrict__ u,
                                                  const float* __restrict__ A_log,
                                                  const float* __restrict__ dt_w,
                                                  const float* __restrict__ dt_b,
                                                  const float* __restrict__ B_w,
                                                  const float* __restrict__ B_b,
                                                  const float* __restrict__ C_w,
                                                  const float* __restrict__ C_b,
                                                  const float* __restrict__ D_w,
                                                  const float* __restrict__ scale,
                                                  const float* __restrict__ init_w,
                                                  const float* __restrict__ init_b,
                                                  float* __restrict__ dt,
                                                  float* __restrict__ Bm,
                                                  float* __restrict__ Cm,
                                                  float* __restrict__ h0,
                                                  float* __restrict__ ap,
                                                  float* __restrict__ hl,
                                                  float* __restrict__ out) {
    cg::grid_group grid = cg::this_grid();
    __shared__ unsigned int As[128 * 16];
    __shared__ unsigned int Bs[128 * 16];
    const int nb = gridDim.x;

    for (int tile = blockIdx.x; tile < 4480; tile += nb)
        phaseA_tile(tile, As, Bs, u, dt_w, dt_b, B_w, B_b, C_w, C_b, init_w, init_b, dt, Bm, Cm, h0);

    __threadfence();
    grid.sync();

    for (int tile = blockIdx.x; tile < 512; tile += nb)
        phaseB_tile(tile, dt, Bm, u, A_log, ap, hl);

    __threadfence();
    grid.sync();

    for (int g = blockIdx.x; g < 256; g += nb)
        phaseC_group(g, h0, ap, hl);

    __threadfence();
    grid.sync();

    for (int tile = blockIdx.x; tile < 512; tile += nb)
        phaseD_tile(tile, dt, Bm, Cm, u, A_log, ap, D_w, scale, out);
}

// ===================== Fallback standalone kernels ===========================
__global__ __launch_bounds__(256) void k_params(const float* __restrict__ u,
                                                const float* __restrict__ dt_w, const float* __restrict__ dt_b,
                                                const float* __restrict__ B_w, const float* __restrict__ B_b,
                                                const float* __restrict__ C_w, const float* __restrict__ C_b,
                                                const float* __restrict__ init_w, const float* __restrict__ init_b,
                                                float* __restrict__ dt, float* __restrict__ Bm,
                                                float* __restrict__ Cm, float* __restrict__ h0) {
    __shared__ unsigned int As[128 * 16];
    __shared__ unsigned int Bs[128 * 16];
    phaseA_tile(blockIdx.x, As, Bs, u, dt_w, dt_b, B_w, B_b, C_w, C_b, init_w, init_b, dt, Bm, Cm, h0);
}

__global__ __launch_bounds__(256) void k_p1(const float* __restrict__ dt, const float* __restrict__ Bm,
                                            const float* __restrict__ u, const float* __restrict__ A_log,
                                            float* __restrict__ ap, float* __restrict__ hl) {
    phaseB_tile(blockIdx.x, dt, Bm, u, A_log, ap, hl);
}

__global__ __launch_bounds__(64) void k_p2(const float* __restrict__ h0,
                                           float* __restrict__ ap, const float* __restrict__ hl) {
    phaseC_group(blockIdx.x, h0, ap, hl);
}

__global__ __launch_bounds__(256) void k_p3(const float* __restrict__ dt, const float* __restrict__ Bm,
                                            const float* __restrict__ Cm, const float* __restrict__ u,
                                            const float* __restrict__ A_log, const float* __restrict__ hstart,
                                            const float* __restrict__ D_w, const float* __restrict__ scale,
                                            float* __restrict__ out) {
    phaseD_tile(blockIdx.x, dt, Bm, Cm, u, A_log, hstart, D_w, scale, out);
}

extern "C" void kernel_launch(void* const* d_in, const int* in_sizes, int n_in,
                              void* d_out, int out_size, void* d_ws, size_t ws_size,
                              hipStream_t stream) {
    const float* u      = (const float*)d_in[0];
    const float* A_log  = (const float*)d_in[1];
    const float* dt_w   = (const float*)d_in[2];
    const float* dt_b   = (const float*)d_in[3];
    const float* B_w    = (const float*)d_in[4];
    const float* B_b    = (const float*)d_in[5];
    const float* C_w    = (const float*)d_in[6];
    const float* C_b    = (const float*)d_in[7];
    const float* D_w    = (const float*)d_in[8];
    const float* scale  = (const float*)d_in[9];
    const float* init_w = (const float*)d_in[10];
    const float* init_b = (const float*)d_in[11];
    float* out = (float*)d_out;

    float* ws = (float*)d_ws;
    float* dt = ws;                        // 2048*1024 = 2097152
    float* Bm = dt + 2097152;              // 32768
    float* Cm = Bm + 32768;                // 32768
    float* h0 = Cm + 32768;                // 16384
    float* ap = h0 + 16384;                // 64*16384 = 1048576
    float* hl = ap + 1048576;              // 1048576

    // Probe cooperative-launch viability (host-side queries: capture-safe,
    // same answer every call -> deterministic path selection).
    int coop = 0;
    (void)hipDeviceGetAttribute(&coop, hipDeviceAttributeCooperativeLaunch, 0);
    int maxBlk = 0;
    (void)hipOccupancyMaxActiveBlocksPerMultiprocessor(&maxBlk, fm_mega, 256, 0);

    hipError_t err = hipErrorUnknown;
    if (coop && maxBlk >= 1) {
        const int grid = (maxBlk >= 2) ? 512 : 256;
        void* args[] = {
            (void*)&u, (void*)&A_log, (void*)&dt_w, (void*)&dt_b,
            (void*)&B_w, (void*)&B_b, (void*)&C_w, (void*)&C_b,
            (void*)&D_w, (void*)&scale, (void*)&init_w, (void*)&init_b,
            (void*)&dt, (void*)&Bm, (void*)&Cm, (void*)&h0,
            (void*)&ap, (void*)&hl, (void*)&out,
        };
        err = hipLaunchCooperativeKernel((void*)fm_mega, dim3(grid), dim3(256), args, 0, stream);
    }
    if (err != hipSuccess) {
        // Fallback: proven 4-dispatch sequence (identical math).
        hipLaunchKernelGGL(k_params, dim3(4480), dim3(256), 0, stream,
                           u, dt_w, dt_b, B_w, B_b, C_w, C_b, init_w, init_b, dt, Bm, Cm, h0);
        hipLaunchKernelGGL(k_p1, dim3(512), dim3(256), 0, stream, dt, Bm, u, A_log, ap, hl);
        hipLaunchKernelGGL(k_p2, dim3(256), dim3(64), 0, stream, h0, ap, hl);
        hipLaunchKernelGGL(k_p3, dim3(512), dim3(256), 0, stream, dt, Bm, Cm, u, A_log, ap, D_w, scale, out);
    }
}

// Round 5
// 119.208 us; speedup vs baseline: 1.2463x; 1.2463x over previous
//
#include <hip/hip_runtime.h>
#include <hip/hip_bf16.h>

typedef __attribute__((ext_vector_type(8))) short short8v;
typedef __attribute__((ext_vector_type(4))) float f32x4;

#define L_SEQ 2048
#define D_DIM 1024
#define N_DIM 16
#define T_CHUNK 32
#define NCHUNK (L_SEQ / T_CHUNK)  // 64
#define EPS_DISC 1e-9f

__device__ __forceinline__ float softplusf(float x) {
    return (x > 15.f) ? x : __logf(1.f + __expf(x));
}

__device__ __forceinline__ unsigned short f2bf(float f) {
    unsigned int u = __float_as_uint(f);
    u += 0x7FFFu + ((u >> 16) & 1u);   // RNE
    return (unsigned short)(u >> 16);
}
__device__ __forceinline__ unsigned int pack2(float a, float b) {
    return (unsigned int)f2bf(a) | ((unsigned int)f2bf(b) << 16);
}

// ============ K_A: fused parameter kernel ====================================
// tiles [0,256)    : dt GEMM, BM=64 x BN=128 x BK=32 (one tile per CU)
// tiles [256,512)  : B/C GEMV
// tiles [512,4608) : h0 matvec (4 rows/tile, 1 row/wave) — HBM/L3 stream
__global__ __launch_bounds__(256) void k_params(const float* __restrict__ u,
                                                const float* __restrict__ dt_w,
                                                const float* __restrict__ dt_b,
                                                const float* __restrict__ B_w,
                                                const float* __restrict__ B_b,
                                                const float* __restrict__ C_w,
                                                const float* __restrict__ C_b,
                                                const float* __restrict__ init_w,
                                                const float* __restrict__ init_b,
                                                float* __restrict__ dt,
                                                float* __restrict__ Bm,
                                                float* __restrict__ Cm,
                                                float* __restrict__ h0) {
    __shared__ unsigned int As[64 * 16];    // 64 rows x 32 bf16, XOR-swizzled
    __shared__ unsigned int Bs[128 * 16];   // 128 rows x 32 bf16, XOR-swizzled
    const int tile = blockIdx.x;
    const int t = threadIdx.x;

    if (tile < 256) {
        // ---- dt GEMM tile: rows bm*64.., cols bn*128.. ----
        const int bm = tile & 31;           // 0..31  (M=2048 / 64)
        const int bn = tile >> 5;           // 0..7   (N=1024 / 128)
        const int lane = t & 63;
        const int wn   = t >> 6;            // wave id 0..3 -> 32-col slice
        const int lrow = lane & 15, lq = lane >> 4;

        // A staging map: row = t>>2 (0..63), q = t&3 -> 8 floats each
        const int arow = t >> 2, aq = t & 3;
        // B staging map: row = t>>1 (0..127), half = t&1 -> 16 floats each
        const int brow = t >> 1, bhalf = t & 1;

        const float* uptr = u + (bm * 64 + arow) * 1024 + aq * 8;
        const float* wptr = dt_w + (bn * 128 + brow) * 1024 + bhalf * 16;

        f32x4 acc[4][2];
#pragma unroll
        for (int mi = 0; mi < 4; ++mi)
#pragma unroll
            for (int ni = 0; ni < 2; ++ni) acc[mi][ni] = (f32x4){0.f, 0.f, 0.f, 0.f};

        for (int k0 = 0; k0 < 1024; k0 += 32) {
            __syncthreads();
            {
                // A: 8 floats -> 1 uint4 (one 8-bf16 k-block)
                const float4* p = (const float4*)(uptr + k0);
                float4 a0 = p[0], a1 = p[1];
                uint4 ca = make_uint4(pack2(a0.x, a0.y), pack2(a0.z, a0.w),
                                      pack2(a1.x, a1.y), pack2(a1.z, a1.w));
                const int akb = aq ^ ((arow >> 1) & 3);
                *(uint4*)&As[arow * 16 + akb * 4] = ca;

                // B: 16 floats -> 2 uint4
                const float4* q = (const float4*)(wptr + k0);
                float4 b0 = q[0], b1 = q[1], b2 = q[2], b3 = q[3];
                uint4 d0 = make_uint4(pack2(b0.x, b0.y), pack2(b0.z, b0.w),
                                      pack2(b1.x, b1.y), pack2(b1.z, b1.w));
                uint4 d1 = make_uint4(pack2(b2.x, b2.y), pack2(b2.z, b2.w),
                                      pack2(b3.x, b3.y), pack2(b3.z, b3.w));
                const int bswz = (brow >> 1) & 3;
                const int kb0 = (bhalf * 2) ^ bswz, kb1 = (bhalf * 2 + 1) ^ bswz;
                *(uint4*)&Bs[brow * 16 + kb0 * 4] = d0;
                *(uint4*)&Bs[brow * 16 + kb1 * 4] = d1;
            }
            __syncthreads();
            short8v af[4], bf[2];
#pragma unroll
            for (int mi = 0; mi < 4; ++mi) {
                const int ar = mi * 16 + lrow;
                const int kb = lq ^ ((ar >> 1) & 3);
                af[mi] = *(const short8v*)&As[ar * 16 + kb * 4];
            }
#pragma unroll
            for (int ni = 0; ni < 2; ++ni) {
                const int br = wn * 32 + ni * 16 + lrow;
                const int kb = lq ^ ((br >> 1) & 3);
                bf[ni] = *(const short8v*)&Bs[br * 16 + kb * 4];
            }
#pragma unroll
            for (int mi = 0; mi < 4; ++mi)
#pragma unroll
                for (int ni = 0; ni < 2; ++ni)
                    acc[mi][ni] = __builtin_amdgcn_mfma_f32_16x16x32_bf16(af[mi], bf[ni], acc[mi][ni], 0, 0, 0);
        }

#pragma unroll
        for (int mi = 0; mi < 4; ++mi)
#pragma unroll
            for (int ni = 0; ni < 2; ++ni) {
                const int cg = bn * 128 + wn * 32 + ni * 16 + lrow;
                const float bv = dt_b[cg];
#pragma unroll
                for (int j = 0; j < 4; ++j) {
                    const int rg = bm * 64 + mi * 16 + lq * 4 + j;
                    dt[rg * 1024 + cg] = softplusf(acc[mi][ni][j] + bv);
                }
            }
    } else if (tile < 512) {
        // ---- B/C GEMV: [2048,16] each ----
        const int tid = (tile - 256) * 256 + t;
        const int l = tid >> 5;
        const int col = tid & 31;
        const float* wrow = (col < 16) ? (B_w + col * 1024) : (C_w + (col - 16) * 1024);
        const float4* w4 = (const float4*)wrow;
        const float4* u4 = (const float4*)(u + l * 1024);
        float acc = 0.f;
#pragma unroll 8
        for (int j = 0; j < 256; ++j) {
            float4 a = u4[j], bb = w4[j];
            acc += a.x * bb.x + a.y * bb.y + a.z * bb.z + a.w * bb.w;
        }
        if (col < 16) Bm[l * 16 + col] = acc + B_b[col];
        else          Cm[l * 16 + (col - 16)] = acc + C_b[col - 16];
    } else {
        // ---- h0 matvec: 16384 rows x 3072, one row per wave ----
        const int lane = t & 63;
        const int row  = (tile - 512) * 4 + (t >> 6);
        const float4* w4 = (const float4*)(init_w + row * 3072);
        const float4* u4 = (const float4*)u;
        float acc = 0.f;
#pragma unroll
        for (int s = 0; s < 12; ++s) {
            float4 a = w4[s * 64 + lane];
            float4 bb = u4[s * 64 + lane];
            acc += a.x * bb.x + a.y * bb.y + a.z * bb.z + a.w * bb.w;
        }
#pragma unroll
        for (int off = 32; off > 0; off >>= 1) acc += __shfl_down(acc, off);
        if (lane == 0) h0[row] = acc + init_b[row];
    }
}

// ============ K_B: phase 1 — per-chunk (prod dA, local h with h_in=0) ========
__global__ __launch_bounds__(256) void k_p1(const float* __restrict__ dt,
                                            const float* __restrict__ Bm,
                                            const float* __restrict__ u,
                                            const float* __restrict__ A_log,
                                            float* __restrict__ ap,
                                            float* __restrict__ hl) {
    const int t    = threadIdx.x;
    const int c    = blockIdx.x >> 3;            // 0..63
    const int dblk = blockIdx.x & 7;             // 0..7
    const int dd   = t >> 1;
    const int nh   = t & 1;
    const int d    = dblk * 128 + dd;
    float An[8];
#pragma unroll
    for (int n = 0; n < 8; ++n) An[n] = -__expf(A_log[nh * 8 + n]);
    float h[8], p[8];
#pragma unroll
    for (int n = 0; n < 8; ++n) { h[n] = 0.f; p[n] = 1.f; }

    const int l0 = c * T_CHUNK;
    for (int i = 0; i < T_CHUNK; ++i) {
        const int l = l0 + i;
        const float dtld = dt[l * D_DIM + d];
        const float uld  = u[l * D_DIM + d];
        const float4 b0 = *(const float4*)&Bm[l * 16 + nh * 8];
        const float4 b1 = *(const float4*)&Bm[l * 16 + nh * 8 + 4];
        auto body = [&](int n, float bn) {
            const float x = dtld * An[n];
            const float e = __expf(x);
            const float coef = (e - 1.f) * __builtin_amdgcn_rcpf(x + EPS_DISC);
            const float bu = coef * bn * uld;
            p[n] *= e;
            h[n] = fmaf(e, h[n], bu);
        };
        body(0, b0.x); body(1, b0.y); body(2, b0.z); body(3, b0.w);
        body(4, b1.x); body(5, b1.y); body(6, b1.z); body(7, b1.w);
    }
    const int base = c * (D_DIM * N_DIM) + d * 16 + nh * 8;
    *(float4*)&ap[base + 0] = make_float4(p[0], p[1], p[2], p[3]);
    *(float4*)&ap[base + 4] = make_float4(p[4], p[5], p[6], p[7]);
    *(float4*)&hl[base + 0] = make_float4(h[0], h[1], h[2], h[3]);
    *(float4*)&hl[base + 4] = make_float4(h[4], h[5], h[6], h[7]);
}

// ============ K_C: phase 2 — chunk-level scan (64 steps) =====================
__global__ __launch_bounds__(64) void k_p2(const float* __restrict__ h0,
                                           float* __restrict__ ap,
                                           const float* __restrict__ hl) {
    const int ch = blockIdx.x * 64 + threadIdx.x;   // 0..16383
    float h = h0[ch];
#pragma unroll 8
    for (int c = 0; c < NCHUNK; ++c) {
        const int idx = c * (D_DIM * N_DIM) + ch;
        const float a = ap[idx];
        const float b = hl[idx];
        ap[idx] = h;            // carry-in for phase 3
        h = fmaf(a, h, b);
    }
}

// ============ K_D: phase 3 — recompute with carry-in, fused epilogue =========
__global__ __launch_bounds__(256) void k_p3(const float* __restrict__ dt,
                                            const float* __restrict__ Bm,
                                            const float* __restrict__ Cm,
                                            const float* __restrict__ u,
                                            const float* __restrict__ A_log,
                                            const float* __restrict__ hstart,
                                            const float* __restrict__ D_w,
                                            const float* __restrict__ scale,
                                            float* __restrict__ out) {
    const int t    = threadIdx.x;
    const int c    = blockIdx.x >> 3;
    const int dblk = blockIdx.x & 7;
    const int dd   = t >> 1;
    const int nh   = t & 1;
    const int d    = dblk * 128 + dd;
    float An[8];
#pragma unroll
    for (int n = 0; n < 8; ++n) An[n] = -__expf(A_log[nh * 8 + n]);
    float h[8];
    const int base = c * (D_DIM * N_DIM) + d * 16 + nh * 8;
    {
        float4 h0v = *(const float4*)&hstart[base + 0];
        float4 h1v = *(const float4*)&hstart[base + 4];
        h[0] = h0v.x; h[1] = h0v.y; h[2] = h0v.z; h[3] = h0v.w;
        h[4] = h1v.x; h[5] = h1v.y; h[6] = h1v.z; h[7] = h1v.w;
    }
    const float scl = fmaxf(scale[0], 0.5f);
    const float dw = D_w[d];
    const int l0 = c * T_CHUNK;
    for (int i = 0; i < T_CHUNK; ++i) {
        const int l = l0 + i;
        const float dtld = dt[l * D_DIM + d];
        const float uld  = u[l * D_DIM + d];
        const float4 b0 = *(const float4*)&Bm[l * 16 + nh * 8];
        const float4 b1 = *(const float4*)&Bm[l * 16 + nh * 8 + 4];
        const float4 c0 = *(const float4*)&Cm[l * 16 + nh * 8];
        const float4 c1 = *(const float4*)&Cm[l * 16 + nh * 8 + 4];
        float y = 0.f;
        auto body = [&](int n, float bn, float cn) {
            const float x = dtld * An[n];
            const float e = __expf(x);
            const float coef = (e - 1.f) * __builtin_amdgcn_rcpf(x + EPS_DISC);
            const float bu = coef * bn * uld;
            h[n] = fmaf(e, h[n], bu);
            y = fmaf(cn, h[n], y);
        };
        body(0, b0.x, c0.x); body(1, b0.y, c0.y); body(2, b0.z, c0.z); body(3, b0.w, c0.w);
        body(4, b1.x, c1.x); body(5, b1.y, c1.y); body(6, b1.z, c1.z); body(7, b1.w, c1.w);
        y += __shfl_xor(y, 1);                 // combine the two n-halves
        if (nh == 0) {
            const float yv = fmaf(dw, uld, y);
            out[l * D_DIM + d] = softplusf(yv) * scl;
        }
    }
}

extern "C" void kernel_launch(void* const* d_in, const int* in_sizes, int n_in,
                              void* d_out, int out_size, void* d_ws, size_t ws_size,
                              hipStream_t stream) {
    const float* u      = (const float*)d_in[0];
    const float* A_log  = (const float*)d_in[1];
    const float* dt_w   = (const float*)d_in[2];
    const float* dt_b   = (const float*)d_in[3];
    const float* B_w    = (const float*)d_in[4];
    const float* B_b    = (const float*)d_in[5];
    const float* C_w    = (const float*)d_in[6];
    const float* C_b    = (const float*)d_in[7];
    const float* D_w    = (const float*)d_in[8];
    const float* scale  = (const float*)d_in[9];
    const float* init_w = (const float*)d_in[10];
    const float* init_b = (const float*)d_in[11];
    float* out = (float*)d_out;

    float* ws = (float*)d_ws;
    float* dt = ws;                        // 2048*1024 = 2097152
    float* Bm = dt + 2097152;              // 32768
    float* Cm = Bm + 32768;                // 32768
    float* h0 = Cm + 32768;                // 16384
    float* ap = h0 + 16384;                // 64*16384 = 1048576
    float* hl = ap + 1048576;              // 1048576

    hipLaunchKernelGGL(k_params, dim3(4608), dim3(256), 0, stream,
                       u, dt_w, dt_b, B_w, B_b, C_w, C_b, init_w, init_b,
                       dt, Bm, Cm, h0);
    hipLaunchKernelGGL(k_p1, dim3(512), dim3(256), 0, stream, dt, Bm, u, A_log, ap, hl);
    hipLaunchKernelGGL(k_p2, dim3(256), dim3(64), 0, stream, h0, ap, hl);
    hipLaunchKernelGGL(k_p3, dim3(512), dim3(256), 0, stream, dt, Bm, Cm, u, A_log, ap, D_w, scale, out);
}

// Round 6
// 111.907 us; speedup vs baseline: 1.3277x; 1.0652x over previous
//
#include <hip/hip_runtime.h>
#include <hip/hip_bf16.h>

typedef __attribute__((ext_vector_type(8))) short short8v;
typedef __attribute__((ext_vector_type(4))) float f32x4;

#define L_SEQ 2048
#define D_DIM 1024
#define N_DIM 16
#define T_CHUNK 32
#define NCHUNK (L_SEQ / T_CHUNK)  // 64
#define EPS_DISC 1e-9f

__device__ __forceinline__ float softplusf(float x) {
    return (x > 15.f) ? x : __logf(1.f + __expf(x));
}

__device__ __forceinline__ unsigned short f2bf(float f) {
    unsigned int u = __float_as_uint(f);
    u += 0x7FFFu + ((u >> 16) & 1u);   // RNE
    return (unsigned short)(u >> 16);
}
__device__ __forceinline__ unsigned int pack2(float a, float b) {
    return (unsigned int)f2bf(a) | ((unsigned int)f2bf(b) << 16);
}

// ============ K_A: fused parameter kernel ====================================
// tiles [0,256)    : dt GEMM, BM=64 x BN=128 x BK=32
// tiles [256,512)  : B/C GEMV
// tiles [512,1536) : h0 matvec SLABS — 16 rows/block, 48 independent float4
//                    loads per thread (latency-tolerant), LDS reduction.
__global__ __launch_bounds__(256) void k_params(const float* __restrict__ u,
                                                const float* __restrict__ dt_w,
                                                const float* __restrict__ dt_b,
                                                const float* __restrict__ B_w,
                                                const float* __restrict__ B_b,
                                                const float* __restrict__ C_w,
                                                const float* __restrict__ C_b,
                                                const float* __restrict__ init_w,
                                                const float* __restrict__ init_b,
                                                float* __restrict__ dt,
                                                float* __restrict__ Bm,
                                                float* __restrict__ Cm,
                                                float* __restrict__ h0) {
    __shared__ unsigned int smem[4096];     // 16 KB, aliased per branch
    const int tile = blockIdx.x;
    const int t = threadIdx.x;

    if (tile < 256) {
        // ---- dt GEMM tile: rows bm*64.., cols bn*128.. ----
        unsigned int* As = smem;            // 64*16 uints
        unsigned int* Bs = smem + 1024;     // 128*16 uints
        const int bm = tile & 31;
        const int bn = tile >> 5;
        const int lane = t & 63;
        const int wn   = t >> 6;
        const int lrow = lane & 15, lq = lane >> 4;

        const int arow = t >> 2, aq = t & 3;
        const int brow = t >> 1, bhalf = t & 1;

        const float* uptr = u + (bm * 64 + arow) * 1024 + aq * 8;
        const float* wptr = dt_w + (bn * 128 + brow) * 1024 + bhalf * 16;

        f32x4 acc[4][2];
#pragma unroll
        for (int mi = 0; mi < 4; ++mi)
#pragma unroll
            for (int ni = 0; ni < 2; ++ni) acc[mi][ni] = (f32x4){0.f, 0.f, 0.f, 0.f};

        for (int k0 = 0; k0 < 1024; k0 += 32) {
            __syncthreads();
            {
                const float4* p = (const float4*)(uptr + k0);
                float4 a0 = p[0], a1 = p[1];
                uint4 ca = make_uint4(pack2(a0.x, a0.y), pack2(a0.z, a0.w),
                                      pack2(a1.x, a1.y), pack2(a1.z, a1.w));
                const int akb = aq ^ ((arow >> 1) & 3);
                *(uint4*)&As[arow * 16 + akb * 4] = ca;

                const float4* q = (const float4*)(wptr + k0);
                float4 b0 = q[0], b1 = q[1], b2 = q[2], b3 = q[3];
                uint4 d0 = make_uint4(pack2(b0.x, b0.y), pack2(b0.z, b0.w),
                                      pack2(b1.x, b1.y), pack2(b1.z, b1.w));
                uint4 d1 = make_uint4(pack2(b2.x, b2.y), pack2(b2.z, b2.w),
                                      pack2(b3.x, b3.y), pack2(b3.z, b3.w));
                const int bswz = (brow >> 1) & 3;
                const int kb0 = (bhalf * 2) ^ bswz, kb1 = (bhalf * 2 + 1) ^ bswz;
                *(uint4*)&Bs[brow * 16 + kb0 * 4] = d0;
                *(uint4*)&Bs[brow * 16 + kb1 * 4] = d1;
            }
            __syncthreads();
            short8v af[4], bf[2];
#pragma unroll
            for (int mi = 0; mi < 4; ++mi) {
                const int ar = mi * 16 + lrow;
                const int kb = lq ^ ((ar >> 1) & 3);
                af[mi] = *(const short8v*)&As[ar * 16 + kb * 4];
            }
#pragma unroll
            for (int ni = 0; ni < 2; ++ni) {
                const int br = wn * 32 + ni * 16 + lrow;
                const int kb = lq ^ ((br >> 1) & 3);
                bf[ni] = *(const short8v*)&Bs[br * 16 + kb * 4];
            }
#pragma unroll
            for (int mi = 0; mi < 4; ++mi)
#pragma unroll
                for (int ni = 0; ni < 2; ++ni)
                    acc[mi][ni] = __builtin_amdgcn_mfma_f32_16x16x32_bf16(af[mi], bf[ni], acc[mi][ni], 0, 0, 0);
        }

#pragma unroll
        for (int mi = 0; mi < 4; ++mi)
#pragma unroll
            for (int ni = 0; ni < 2; ++ni) {
                const int cg = bn * 128 + wn * 32 + ni * 16 + lrow;
                const float bv = dt_b[cg];
#pragma unroll
                for (int j = 0; j < 4; ++j) {
                    const int rg = bm * 64 + mi * 16 + lq * 4 + j;
                    dt[rg * 1024 + cg] = softplusf(acc[mi][ni][j] + bv);
                }
            }
    } else if (tile < 512) {
        // ---- B/C GEMV: [2048,16] each ----
        const int tid = (tile - 256) * 256 + t;
        const int l = tid >> 5;
        const int col = tid & 31;
        const float* wrow = (col < 16) ? (B_w + col * 1024) : (C_w + (col - 16) * 1024);
        const float4* w4 = (const float4*)wrow;
        const float4* u4 = (const float4*)(u + l * 1024);
        float acc = 0.f;
#pragma unroll 8
        for (int j = 0; j < 256; ++j) {
            float4 a = u4[j], bb = w4[j];
            acc += a.x * bb.x + a.y * bb.y + a.z * bb.z + a.w * bb.w;
        }
        if (col < 16) Bm[l * 16 + col] = acc + B_b[col];
        else          Cm[l * 16 + (col - 16)] = acc + C_b[col - 16];
    } else {
        // ---- h0 matvec slab: 16 rows x 3072; 48 independent loads/thread ----
        const int slab = tile - 512;                 // 0..1023
        float* sf = (float*)smem;

        // stage u_prefix (3072 floats) into LDS
        {
            const float4* u4 = (const float4*)u;
            float4* s4 = (float4*)sf;
            s4[t]       = u4[t];
            s4[t + 256] = u4[t + 256];
            s4[t + 512] = u4[t + 512];
        }
        __syncthreads();
        const float4 bb0 = ((const float4*)sf)[t];
        const float4 bb1 = ((const float4*)sf)[t + 256];
        const float4 bb2 = ((const float4*)sf)[t + 512];

        const float4* w4 = (const float4*)init_w + (size_t)slab * 12288 + t;
        float pr[16];
#pragma unroll 4
        for (int q = 0; q < 16; ++q) {
            const float4 a0 = w4[q * 768];
            const float4 a1 = w4[q * 768 + 256];
            const float4 a2 = w4[q * 768 + 512];
            pr[q] = a0.x * bb0.x + a0.y * bb0.y + a0.z * bb0.z + a0.w * bb0.w
                  + a1.x * bb1.x + a1.y * bb1.y + a1.z * bb1.z + a1.w * bb1.w
                  + a2.x * bb2.x + a2.y * bb2.y + a2.z * bb2.z + a2.w * bb2.w;
        }
        __syncthreads();                 // done with staged u
#pragma unroll
        for (int q = 0; q < 16; ++q) sf[q * 256 + t] = pr[q];
        __syncthreads();
        const int r = t >> 4, i = t & 15;
        float s = 0.f;
#pragma unroll
        for (int j = 0; j < 16; ++j) s += sf[r * 256 + i * 16 + j];
#pragma unroll
        for (int m = 8; m >= 1; m >>= 1) s += __shfl_xor(s, m, 16);
        if (i == 0) {
            const int row = slab * 16 + r;
            h0[row] = s + init_b[row];
        }
    }
}

// ============ K_B: phase 1 — per-chunk (prod dA, local h with h_in=0) ========
__global__ __launch_bounds__(256) void k_p1(const float* __restrict__ dt,
                                            const float* __restrict__ Bm,
                                            const float* __restrict__ u,
                                            const float* __restrict__ A_log,
                                            float* __restrict__ ap,
                                            float* __restrict__ hl) {
    const int t    = threadIdx.x;
    const int c    = blockIdx.x >> 3;            // 0..63
    const int dblk = blockIdx.x & 7;             // 0..7
    const int dd   = t >> 1;
    const int nh   = t & 1;
    const int d    = dblk * 128 + dd;
    float An[8];
#pragma unroll
    for (int n = 0; n < 8; ++n) An[n] = -__expf(A_log[nh * 8 + n]);
    float h[8], p[8];
#pragma unroll
    for (int n = 0; n < 8; ++n) { h[n] = 0.f; p[n] = 1.f; }

    const int l0 = c * T_CHUNK;
    for (int i = 0; i < T_CHUNK; ++i) {
        const int l = l0 + i;
        const float dtld = dt[l * D_DIM + d];
        const float uld  = u[l * D_DIM + d];
        const float4 b0 = *(const float4*)&Bm[l * 16 + nh * 8];
        const float4 b1 = *(const float4*)&Bm[l * 16 + nh * 8 + 4];
        auto body = [&](int n, float bn) {
            const float x = dtld * An[n];
            const float e = __expf(x);
            const float coef = (e - 1.f) * __builtin_amdgcn_rcpf(x + EPS_DISC);
            const float bu = coef * bn * uld;
            p[n] *= e;
            h[n] = fmaf(e, h[n], bu);
        };
        body(0, b0.x); body(1, b0.y); body(2, b0.z); body(3, b0.w);
        body(4, b1.x); body(5, b1.y); body(6, b1.z); body(7, b1.w);
    }
    const int base = c * (D_DIM * N_DIM) + d * 16 + nh * 8;
    *(float4*)&ap[base + 0] = make_float4(p[0], p[1], p[2], p[3]);
    *(float4*)&ap[base + 4] = make_float4(p[4], p[5], p[6], p[7]);
    *(float4*)&hl[base + 0] = make_float4(h[0], h[1], h[2], h[3]);
    *(float4*)&hl[base + 4] = make_float4(h[4], h[5], h[6], h[7]);
}

// ============ K_C: phase 2 — chunk-level scan (64 steps) =====================
__global__ __launch_bounds__(64) void k_p2(const float* __restrict__ h0,
                                           float* __restrict__ ap,
                                           const float* __restrict__ hl) {
    const int ch = blockIdx.x * 64 + threadIdx.x;   // 0..16383
    float h = h0[ch];
#pragma unroll 8
    for (int c = 0; c < NCHUNK; ++c) {
        const int idx = c * (D_DIM * N_DIM) + ch;
        const float a = ap[idx];
        const float b = hl[idx];
        ap[idx] = h;            // carry-in for phase 3
        h = fmaf(a, h, b);
    }
}

// ============ K_D: phase 3 — recompute with carry-in, fused epilogue =========
__global__ __launch_bounds__(256) void k_p3(const float* __restrict__ dt,
                                            const float* __restrict__ Bm,
                                            const float* __restrict__ Cm,
                                            const float* __restrict__ u,
                                            const float* __restrict__ A_log,
                                            const float* __restrict__ hstart,
                                            const float* __restrict__ D_w,
                                            const float* __restrict__ scale,
                                            float* __restrict__ out) {
    const int t    = threadIdx.x;
    const int c    = blockIdx.x >> 3;
    const int dblk = blockIdx.x & 7;
    const int dd   = t >> 1;
    const int nh   = t & 1;
    const int d    = dblk * 128 + dd;
    float An[8];
#pragma unroll
    for (int n = 0; n < 8; ++n) An[n] = -__expf(A_log[nh * 8 + n]);
    float h[8];
    const int base = c * (D_DIM * N_DIM) + d * 16 + nh * 8;
    {
        float4 h0v = *(const float4*)&hstart[base + 0];
        float4 h1v = *(const float4*)&hstart[base + 4];
        h[0] = h0v.x; h[1] = h0v.y; h[2] = h0v.z; h[3] = h0v.w;
        h[4] = h1v.x; h[5] = h1v.y; h[6] = h1v.z; h[7] = h1v.w;
    }
    const float scl = fmaxf(scale[0], 0.5f);
    const float dw = D_w[d];
    const int l0 = c * T_CHUNK;
    for (int i = 0; i < T_CHUNK; ++i) {
        const int l = l0 + i;
        const float dtld = dt[l * D_DIM + d];
        const float uld  = u[l * D_DIM + d];
        const float4 b0 = *(const float4*)&Bm[l * 16 + nh * 8];
        const float4 b1 = *(const float4*)&Bm[l * 16 + nh * 8 + 4];
        const float4 c0 = *(const float4*)&Cm[l * 16 + nh * 8];
        const float4 c1 = *(const float4*)&Cm[l * 16 + nh * 8 + 4];
        float y = 0.f;
        auto body = [&](int n, float bn, float cn) {
            const float x = dtld * An[n];
            const float e = __expf(x);
            const float coef = (e - 1.f) * __builtin_amdgcn_rcpf(x + EPS_DISC);
            const float bu = coef * bn * uld;
            h[n] = fmaf(e, h[n], bu);
            y = fmaf(cn, h[n], y);
        };
        body(0, b0.x, c0.x); body(1, b0.y, c0.y); body(2, b0.z, c0.z); body(3, b0.w, c0.w);
        body(4, b1.x, c1.x); body(5, b1.y, c1.y); body(6, b1.z, c1.z); body(7, b1.w, c1.w);
        y += __shfl_xor(y, 1);                 // combine the two n-halves
        if (nh == 0) {
            const float yv = fmaf(dw, uld, y);
            out[l * D_DIM + d] = softplusf(yv) * scl;
        }
    }
}

extern "C" void kernel_launch(void* const* d_in, const int* in_sizes, int n_in,
                              void* d_out, int out_size, void* d_ws, size_t ws_size,
                              hipStream_t stream) {
    const float* u      = (const float*)d_in[0];
    const float* A_log  = (const float*)d_in[1];
    const float* dt_w   = (const float*)d_in[2];
    const float* dt_b   = (const float*)d_in[3];
    const float* B_w    = (const float*)d_in[4];
    const float* B_b    = (const float*)d_in[5];
    const float* C_w    = (const float*)d_in[6];
    const float* C_b    = (const float*)d_in[7];
    const float* D_w    = (const float*)d_in[8];
    const float* scale  = (const float*)d_in[9];
    const float* init_w = (const float*)d_in[10];
    const float* init_b = (const float*)d_in[11];
    float* out = (float*)d_out;

    float* ws = (float*)d_ws;
    float* dt = ws;                        // 2048*1024 = 2097152
    float* Bm = dt + 2097152;              // 32768
    float* Cm = Bm + 32768;                // 32768
    float* h0 = Cm + 32768;                // 16384
    float* ap = h0 + 16384;                // 64*16384 = 1048576
    float* hl = ap + 1048576;              // 1048576

    hipLaunchKernelGGL(k_params, dim3(1536), dim3(256), 0, stream,
                       u, dt_w, dt_b, B_w, B_b, C_w, C_b, init_w, init_b,
                       dt, Bm, Cm, h0);
    hipLaunchKernelGGL(k_p1, dim3(512), dim3(256), 0, stream, dt, Bm, u, A_log, ap, hl);
    hipLaunchKernelGGL(k_p2, dim3(256), dim3(64), 0, stream, h0, ap, hl);
    hipLaunchKernelGGL(k_p3, dim3(512), dim3(256), 0, stream, dt, Bm, Cm, u, A_log, ap, D_w, scale, out);
}